// Round 1
// baseline (435.463 us; speedup 1.0000x reference)
//
#include <hip/hip_runtime.h>
#include <math.h>

#define B_    32
#define C_    256
#define HF    64
#define WF    64
#define M_    4096   // HF*WF
#define N_    128
#define IMGM1 1023.0f
#define TEMP_ 0.1f
#define EPS_  1e-12f
#define NCH   32     // m-chunks in k2 = M_/128

__device__ __forceinline__ float wave_sum(float v) {
#pragma unroll
  for (int off = 32; off; off >>= 1) v += __shfl_down(v, off, 64);
  return v;
}
__device__ __forceinline__ float wave_max(float v) {
#pragma unroll
  for (int off = 32; off; off >>= 1) v = fmaxf(v, __shfl_down(v, off, 64));
  return v;
}

// ---------------- k1: q[b,n,c] = bilinear sample of channel-normalized feats_src ----------------
__global__ __launch_bounds__(256) void k1_sample_q(const float* __restrict__ fs,
                                                   const float* __restrict__ kps,
                                                   float* __restrict__ q) {
  const int n = blockIdx.x, b = blockIdx.y, c = threadIdx.x;
  const float kx = kps[((size_t)b * N_ + n) * 2 + 0];
  const float ky = kps[((size_t)b * N_ + n) * 2 + 1];
  const float x = kx / IMGM1 * (float)(WF - 1);
  const float y = ky / IMGM1 * (float)(HF - 1);
  const int x0 = (int)fminf(fmaxf(floorf(x), 0.f), (float)(WF - 1));
  const int y0 = (int)fminf(fmaxf(floorf(y), 0.f), (float)(HF - 1));
  const int x1 = min(x0 + 1, WF - 1), y1 = min(y0 + 1, HF - 1);
  const float fx = x - (float)x0, fy = y - (float)y0;
  const float wa = (1.f - fx) * (1.f - fy), wb = (1.f - fx) * fy;
  const float wc = fx * (1.f - fy), wd = fx * fy;

  const float* base = fs + ((size_t)b * C_ + c) * M_;
  const float f00 = base[y0 * WF + x0];   // weight wa
  const float f10 = base[y1 * WF + x0];   // weight wb
  const float f01 = base[y0 * WF + x1];   // weight wc
  const float f11 = base[y1 * WF + x1];   // weight wd

  float s0 = wave_sum(f00 * f00);
  float s1 = wave_sum(f10 * f10);
  float s2 = wave_sum(f01 * f01);
  float s3 = wave_sum(f11 * f11);

  __shared__ float wsum[4][4];
  __shared__ float rinv[4];
  const int lane = c & 63, wid = c >> 6;
  if (lane == 0) { wsum[wid][0] = s0; wsum[wid][1] = s1; wsum[wid][2] = s2; wsum[wid][3] = s3; }
  __syncthreads();
  if (c < 4) {
    float tt = wsum[0][c] + wsum[1][c] + wsum[2][c] + wsum[3][c];
    rinv[c] = 1.f / fmaxf(sqrtf(tt), EPS_);
  }
  __syncthreads();
  const float qv = wa * f00 * rinv[0] + wb * f10 * rinv[1] + wc * f01 * rinv[2] + wd * f11 * rinv[3];
  q[((size_t)b * N_ + n) * C_ + c] = qv;
}

// ---------------- k2: per-(b, 128-m chunk): logits tile + online softmax partials ----------------
// logits[n,m] = (q[n,:] . trg[:,m]) / (max(||trg[:,m]||,eps) * TEMP)
// Emits part[b][n][chunk] = (chunk_max, chunk_sumexp) as float2.
__global__ __launch_bounds__(256) void k2_logits(const float* __restrict__ trg,
                                                 const float* __restrict__ q,
                                                 float2* __restrict__ part) {
  const int t = threadIdx.x;
  const int mb = blockIdx.x, b = blockIdx.y;
  const int m0 = mb * 128;
  const int tn = t >> 4, tm = t & 15;

  __shared__ float sA[16 * 132];  // [kc=16][n=128 +4 pad], transposed A
  __shared__ float sB[16 * 132];  // [kc=16][m=128 +4 pad]

  float acc[8][8];
#pragma unroll
  for (int i = 0; i < 8; i++)
#pragma unroll
    for (int j = 0; j < 8; j++) acc[i][j] = 0.f;

  float ssq_p = 0.f;  // partial sum-of-squares for column m = t&127
  const float* qb = q + (size_t)b * N_ * C_;
  const float* tb = trg + (size_t)b * C_ * M_ + m0;

  for (int k0 = 0; k0 < C_; k0 += 16) {
#pragma unroll
    for (int i = 0; i < 8; i++) {
      const int e = t + 256 * i;
      const int c = e & 15, n = e >> 4;
      sA[c * 132 + n] = qb[n * C_ + k0 + c];
    }
#pragma unroll
    for (int i = 0; i < 8; i++) {
      const int e = t + 256 * i;
      const int m = e & 127, cc = e >> 7;
      const float v = tb[(size_t)(k0 + cc) * M_ + m];
      sB[cc * 132 + m] = v;
      ssq_p += v * v;
    }
    __syncthreads();
#pragma unroll
    for (int kk = 0; kk < 16; kk++) {
      const float4 a0 = *(const float4*)&sA[kk * 132 + tn * 8];
      const float4 a1 = *(const float4*)&sA[kk * 132 + tn * 8 + 4];
      const float4 b0 = *(const float4*)&sB[kk * 132 + tm * 8];
      const float4 b1 = *(const float4*)&sB[kk * 132 + tm * 8 + 4];
      const float av[8] = {a0.x, a0.y, a0.z, a0.w, a1.x, a1.y, a1.z, a1.w};
      const float bv[8] = {b0.x, b0.y, b0.z, b0.w, b1.x, b1.y, b1.z, b1.w};
#pragma unroll
      for (int i = 0; i < 8; i++)
#pragma unroll
        for (int j = 0; j < 8; j++) acc[i][j] = fmaf(av[i], bv[j], acc[i][j]);
    }
    __syncthreads();
  }

  // combine ssq (threads t and t+128 hold partials for column t&127)
  __shared__ float ssq2[256];
  __shared__ float scl[128];
  __shared__ float red[128 * 17];
  __shared__ float rowmax[128];
  ssq2[t] = ssq_p;
  __syncthreads();
  if (t < 128) scl[t] = 1.f / (fmaxf(sqrtf(ssq2[t] + ssq2[t + 128]), EPS_) * TEMP_);
  __syncthreads();

  float sc[8];
#pragma unroll
  for (int j = 0; j < 8; j++) sc[j] = scl[tm * 8 + j];

#pragma unroll
  for (int i = 0; i < 8; i++) {
    float mx = -INFINITY;
#pragma unroll
    for (int j = 0; j < 8; j++) {
      acc[i][j] *= sc[j];
      mx = fmaxf(mx, acc[i][j]);
    }
    red[(tn * 8 + i) * 17 + tm] = mx;
  }
  __syncthreads();
  if (t < 128) {
    float mx = -INFINITY;
#pragma unroll
    for (int k = 0; k < 16; k++) mx = fmaxf(mx, red[t * 17 + k]);
    rowmax[t] = mx;
  }
  __syncthreads();
#pragma unroll
  for (int i = 0; i < 8; i++) {
    const float gm = rowmax[tn * 8 + i];
    float s = 0.f;
#pragma unroll
    for (int j = 0; j < 8; j++) s += __expf(acc[i][j] - gm);
    red[(tn * 8 + i) * 17 + tm] = s;
  }
  __syncthreads();
  if (t < 128) {
    float s = 0.f;
#pragma unroll
    for (int k = 0; k < 16; k++) s += red[t * 17 + k];
    part[((size_t)b * N_ + t) * NCH + mb] = make_float2(rowmax[t], s);
  }
}

// ---------------- k3: combine LSE, recompute 4 target logits, per-(b,n) loss ----------------
__global__ __launch_bounds__(64) void k3_loss(const float* __restrict__ trg,
                                              const float* __restrict__ q,
                                              const float* __restrict__ kps_trg,
                                              const int* __restrict__ mask,
                                              const float2* __restrict__ part,
                                              float* __restrict__ loss) {
  const int n = blockIdx.x, b = blockIdx.y, lane = threadIdx.x;

  // logsumexp over all 4096 m from 32 chunk partials
  float pm = -INFINITY, ps = 0.f;
  if (lane < NCH) {
    const float2 v = part[((size_t)b * N_ + n) * NCH + lane];
    pm = v.x;
    ps = v.y;
  }
  float gm = wave_max(pm);
  gm = __shfl(gm, 0, 64);
  float tot = wave_sum(ps * __expf(pm - gm));
  tot = __shfl(tot, 0, 64);
  const float lse = gm + logf(tot);

  // target bilinear geometry (feature-grid coords, STRIDE=16)
  const float kx = kps_trg[((size_t)b * N_ + n) * 2 + 0];
  const float ky = kps_trg[((size_t)b * N_ + n) * 2 + 1];
  const float gx = kx * (1.f / 16.f), gy = ky * (1.f / 16.f);
  const int x0 = (int)fminf(fmaxf(floorf(gx), 0.f), (float)(WF - 1));
  const int y0 = (int)fminf(fmaxf(floorf(gy), 0.f), (float)(HF - 1));
  const int x1 = min(x0 + 1, WF - 1), y1 = min(y0 + 1, HF - 1);
  const float x0f = (float)x0, x1f = (float)x1, y0f = (float)y0, y1f = (float)y1;
  const float mk = (mask[(size_t)b * N_ + n] != 0) ? 1.f : 0.f;
  const float w[4] = {(x1f - gx) * (y1f - gy) * mk, (x1f - gx) * (gy - y0f) * mk,
                      (gx - x0f) * (y1f - gy) * mk, (gx - x0f) * (gy - y0f) * mk};
  const int idx[4] = {y0 * WF + x0, y1 * WF + x0, y0 * WF + x1, y1 * WF + x1};

  const float* qn = q + ((size_t)b * N_ + n) * C_;
  const float4 qv = ((const float4*)qn)[lane];  // c = lane*4 .. lane*4+3
  const float* tb = trg + (size_t)b * C_ * M_;
  const int c0 = lane * 4;

  float lsum = 0.f, wsum = 0.f;
#pragma unroll
  for (int j = 0; j < 4; j++) {
    const float t0 = tb[(size_t)(c0 + 0) * M_ + idx[j]];
    const float t1 = tb[(size_t)(c0 + 1) * M_ + idx[j]];
    const float t2 = tb[(size_t)(c0 + 2) * M_ + idx[j]];
    const float t3 = tb[(size_t)(c0 + 3) * M_ + idx[j]];
    float d = qv.x * t0 + qv.y * t1 + qv.z * t2 + qv.w * t3;
    float s = t0 * t0 + t1 * t1 + t2 * t2 + t3 * t3;
    d = wave_sum(d);
    s = wave_sum(s);
    if (lane == 0) {
      const float logit = d / (fmaxf(sqrtf(s), EPS_) * TEMP_);
      lsum += w[j] * logit;
      wsum += w[j];
    }
  }
  if (lane == 0) loss[(size_t)b * N_ + n] = wsum * lse - lsum;
}

// ---------------- k4: masked mean ----------------
__global__ __launch_bounds__(256) void k4_reduce(const float* __restrict__ loss,
                                                 const int* __restrict__ mask,
                                                 float* __restrict__ out) {
  const int t = threadIdx.x;
  float ls = 0.f, ms = 0.f;
  for (int i = t; i < B_ * N_; i += 256) {
    ls += loss[i];
    ms += (mask[i] != 0) ? 1.f : 0.f;
  }
  ls = wave_sum(ls);
  ms = wave_sum(ms);
  __shared__ float l4[4], m4[4];
  const int lane = t & 63, wid = t >> 6;
  if (lane == 0) { l4[wid] = ls; m4[wid] = ms; }
  __syncthreads();
  if (t == 0) {
    const float L = l4[0] + l4[1] + l4[2] + l4[3];
    const float Mm = m4[0] + m4[1] + m4[2] + m4[3];
    out[0] = L / fmaxf(Mm, 1.f);
  }
}

extern "C" void kernel_launch(void* const* d_in, const int* in_sizes, int n_in,
                              void* d_out, int out_size, void* d_ws, size_t ws_size,
                              hipStream_t stream) {
  const float* feats_src = (const float*)d_in[0];
  const float* feats_trg = (const float*)d_in[1];
  const float* kps_src   = (const float*)d_in[2];
  const float* kps_trg   = (const float*)d_in[3];
  const int*   kps_mask  = (const int*)d_in[4];
  float* out = (float*)d_out;

  // workspace layout (floats): q [B*N*C] | part [B*N*NCH float2] | loss [B*N]
  float*  ws   = (float*)d_ws;
  float*  q    = ws;                                   // 1,048,576 floats
  float2* part = (float2*)(ws + (size_t)B_ * N_ * C_); // 131,072 float2
  float*  loss = ws + (size_t)B_ * N_ * C_ + (size_t)B_ * N_ * NCH * 2;  // 4096 floats

  k1_sample_q<<<dim3(N_, B_), 256, 0, stream>>>(feats_src, kps_src, q);
  k2_logits<<<dim3(M_ / 128, B_), 256, 0, stream>>>(feats_trg, q, part);
  k3_loss<<<dim3(N_, B_), 64, 0, stream>>>(feats_trg, q, kps_trg, kps_mask, part, loss);
  k4_reduce<<<1, 256, 0, stream>>>(loss, kps_mask, out);
}

// Round 2
// 345.934 us; speedup vs baseline: 1.2588x; 1.2588x over previous
//
#include <hip/hip_runtime.h>
#include <math.h>

#define B_    32
#define C_    256
#define HF    64
#define WF    64
#define M_    4096   // HF*WF
#define N_    128
#define IMGM1 1023.0f
#define TEMP_ 0.1f
#define EPS_  1e-12f
#define NCH   32     // m-chunks in k2 = M_/128
#define SAS   40     // LDS row stride (shorts) for sA/sB: 80 B -> 2-way bank alias only

typedef __attribute__((ext_vector_type(8))) short short8;
typedef __attribute__((ext_vector_type(4))) float floatx4;

__device__ __forceinline__ unsigned short f2bf(float x) {  // RNE fp32->bf16
  unsigned int u = __float_as_uint(x);
  u += 0x7fffu + ((u >> 16) & 1u);
  return (unsigned short)(u >> 16);
}
__device__ __forceinline__ float bf2f(unsigned short h) {
  return __uint_as_float(((unsigned int)h) << 16);
}
__device__ __forceinline__ float wave_sum(float v) {
#pragma unroll
  for (int off = 32; off; off >>= 1) v += __shfl_down(v, off, 64);
  return v;
}

__device__ __forceinline__ void src_geom(float kx, float ky, int& x0, int& y0,
                                         int& x1, int& y1, float& fx, float& fy) {
  const float x = kx / IMGM1 * (float)(WF - 1);
  const float y = ky / IMGM1 * (float)(HF - 1);
  x0 = (int)fminf(fmaxf(floorf(x), 0.f), 63.f);
  y0 = (int)fminf(fmaxf(floorf(y), 0.f), 63.f);
  x1 = min(x0 + 1, 63);
  y1 = min(y0 + 1, 63);
  fx = x - (float)x0;
  fy = y - (float)y0;
}

// ============ k1a: coalesced plane staging -> corner gather (bf16) + ssq atomics ============
// grid (C_/2, B_), block 256. Reads feats_src exactly once, coalesced.
__global__ __launch_bounds__(256) void k1a_stage(const float* __restrict__ fs,
                                                 const float* __restrict__ kps,
                                                 ushort* __restrict__ corner,
                                                 float* __restrict__ ssqg) {
  const int cg = blockIdx.x, b = blockIdx.y, t = threadIdx.x;
  const int c0 = cg * 2;
  __shared__ __align__(16) float plane[2 * M_];   // 32 KB: 2 channel planes
  __shared__ float4 ssq2[256];

  const float4* src = (const float4*)(fs + ((size_t)(b * C_ + c0)) * M_);
  float4* dst = (float4*)plane;
#pragma unroll
  for (int i = 0; i < 8; i++) dst[t + 256 * i] = src[t + 256 * i];
  __syncthreads();

  const int n = t & 127, p = t >> 7;
  const int c = c0 + p;
  const float kx = kps[((size_t)b * N_ + n) * 2 + 0];
  const float ky = kps[((size_t)b * N_ + n) * 2 + 1];
  int x0, y0, x1, y1; float fx, fy;
  src_geom(kx, ky, x0, y0, x1, y1, fx, fy);

  const float* pl = plane + p * M_;
  const float f00 = pl[y0 * WF + x0];
  const float f10 = pl[y1 * WF + x0];
  const float f01 = pl[y0 * WF + x1];
  const float f11 = pl[y1 * WF + x1];

  // coalesced bf16 corner store: corner[b][c][n][4]
  ushort4 cr;
  cr.x = f2bf(f00); cr.y = f2bf(f10); cr.z = f2bf(f01); cr.w = f2bf(f11);
  *(ushort4*)&corner[(((size_t)b * C_ + c) * N_ + n) * 4] = cr;

  ssq2[t] = make_float4(f00 * f00, f10 * f10, f01 * f01, f11 * f11);
  __syncthreads();
  if (t < 128) {
    const float4 a = ssq2[t], bq = ssq2[t + 128];
    float* g = ssqg + ((size_t)b * N_ + t) * 4;
    atomicAdd(g + 0, a.x + bq.x);
    atomicAdd(g + 1, a.y + bq.y);
    atomicAdd(g + 2, a.z + bq.z);
    atomicAdd(g + 3, a.w + bq.w);
  }
}

// ============ k1b: normalize + bilinear blend -> q (bf16, [b][n][c]) ============
__global__ __launch_bounds__(256) void k1b_combine(const ushort* __restrict__ corner,
                                                   const float* __restrict__ ssqg,
                                                   const float* __restrict__ kps,
                                                   ushort* __restrict__ qbf) {
  const int n = blockIdx.x, b = blockIdx.y, c = threadIdx.x;
  const float kx = kps[((size_t)b * N_ + n) * 2 + 0];
  const float ky = kps[((size_t)b * N_ + n) * 2 + 1];
  int x0, y0, x1, y1; float fx, fy;
  src_geom(kx, ky, x0, y0, x1, y1, fx, fy);
  const float wa = (1.f - fx) * (1.f - fy), wb = (1.f - fx) * fy;
  const float wc = fx * (1.f - fy), wd = fx * fy;

  const float4 sq = *(const float4*)&ssqg[((size_t)b * N_ + n) * 4];
  const float r0 = 1.f / fmaxf(sqrtf(sq.x), EPS_);
  const float r1 = 1.f / fmaxf(sqrtf(sq.y), EPS_);
  const float r2 = 1.f / fmaxf(sqrtf(sq.z), EPS_);
  const float r3 = 1.f / fmaxf(sqrtf(sq.w), EPS_);

  const ushort4 cr = *(const ushort4*)&corner[(((size_t)b * C_ + c) * N_ + n) * 4];
  const float qv = wa * bf2f(cr.x) * r0 + wb * bf2f(cr.y) * r1 +
                   wc * bf2f(cr.z) * r2 + wd * bf2f(cr.w) * r3;
  qbf[((size_t)b * N_ + n) * C_ + c] = f2bf(qv);
}

// ============ k2: bf16 MFMA logits + trg norms + online softmax partials + target logits ============
// grid (NCH, B_), block 256 (4 waves, each a 64x64 output region of the 128n x 128m tile)
__global__ __launch_bounds__(256) void k2_mfma(const float* __restrict__ trg,
                                               const ushort* __restrict__ qbf,
                                               const float* __restrict__ kps_trg,
                                               const int* __restrict__ mask,
                                               float2* __restrict__ part,
                                               float* __restrict__ tacc) {
  const int t = threadIdx.x;
  const int mb = blockIdx.x, b = blockIdx.y;
  const int m0 = mb * 128;
  const int wave = t >> 6, lane = t & 63;
  const int wn = wave >> 1, wm = wave & 1;
  const int lg = lane >> 4, ln = lane & 15;

  __shared__ __align__(16) short sA[128 * SAS];      // q tile   [n][k], padded
  __shared__ __align__(16) short sB[128 * SAS];      // trg^T    [m][k], padded + 16B XOR swizzle
  __shared__ __align__(16) float ssqp[16 * 128];
  __shared__ float scl[128];
  __shared__ float2 lser[128 * 2];
  __shared__ __align__(16) int   tidx[128][4];
  __shared__ __align__(16) float tw[128][4];

  floatx4 acc[4][4];
#pragma unroll
  for (int i = 0; i < 4; i++)
#pragma unroll
    for (int j = 0; j < 4; j++) acc[i][j] = (floatx4)0.f;

  float ssq[8];
#pragma unroll
  for (int e = 0; e < 8; e++) ssq[e] = 0.f;

  const ushort* qb = qbf + (size_t)b * N_ * C_;
  const float*  tb = trg + (size_t)b * C_ * M_ + m0;
  const int kk  = 2 * (t >> 4);       // k-pair row for B staging
  const int m8  = (t & 15) * 8;       // 8-column group for B staging
  const int gB  = kk >> 3;            // 16B chunk containing this k-pair
  const int kin = kk & 7;

  for (int k0 = 0; k0 < C_; k0 += 32) {
    // --- A staging: 128x32 bf16, contiguous 16B loads/stores ---
#pragma unroll
    for (int l2 = 0; l2 < 2; l2++) {
      const int flat = t + 256 * l2;
      const int an = flat >> 2, ag = flat & 3;
      const short8 v = *(const short8*)(qb + an * C_ + k0 + ag * 8);
      *(short8*)&sA[an * SAS + ag * 8] = v;
    }
    // --- B staging: transpose 32x128 fp32 -> [m][k] bf16 pairs, XOR-swizzled chunks ---
    {
      const float* p0 = tb + (size_t)(k0 + kk) * M_ + m8;
      const float* p1 = p0 + M_;
      const float4 a0 = *(const float4*)p0, a1 = *(const float4*)(p0 + 4);
      const float4 b0 = *(const float4*)p1, b1 = *(const float4*)(p1 + 4);
      const float v0[8] = {a0.x, a0.y, a0.z, a0.w, a1.x, a1.y, a1.z, a1.w};
      const float v1[8] = {b0.x, b0.y, b0.z, b0.w, b1.x, b1.y, b1.z, b1.w};
#pragma unroll
      for (int e = 0; e < 8; e++) {
        ssq[e] += v0[e] * v0[e] + v1[e] * v1[e];
        const int m = m8 + e;
        const int fm = (m >> 3) & 3;
        const unsigned int pr = (unsigned int)f2bf(v0[e]) | ((unsigned int)f2bf(v1[e]) << 16);
        *(unsigned int*)&sB[m * SAS + ((gB ^ fm) << 3) + kin] = pr;
      }
    }
    __syncthreads();
    short8 af[4], bfr[4];
#pragma unroll
    for (int i = 0; i < 4; i++)
      af[i] = *(const short8*)&sA[(wn * 64 + i * 16 + ln) * SAS + (lg << 3)];
#pragma unroll
    for (int j = 0; j < 4; j++) {
      const int m = wm * 64 + j * 16 + ln;
      const int fm = (m >> 3) & 3;
      bfr[j] = *(const short8*)&sB[m * SAS + ((lg ^ fm) << 3)];
    }
#pragma unroll
    for (int i = 0; i < 4; i++)
#pragma unroll
      for (int j = 0; j < 4; j++)
        acc[i][j] = __builtin_amdgcn_mfma_f32_16x16x32_bf16(af[i], bfr[j], acc[i][j], 0, 0, 0);
    __syncthreads();
  }

  // --- column norms -> scale ---
  *(float4*)&ssqp[(t >> 4) * 128 + m8]     = make_float4(ssq[0], ssq[1], ssq[2], ssq[3]);
  *(float4*)&ssqp[(t >> 4) * 128 + m8 + 4] = make_float4(ssq[4], ssq[5], ssq[6], ssq[7]);
  __syncthreads();
  if (t < 128) {
    float s = 0.f;
#pragma unroll
    for (int g = 0; g < 16; g++) s += ssqp[g * 128 + t];
    scl[t] = 1.f / (fmaxf(sqrtf(s), EPS_) * TEMP_);
    // target keypoint geometry for n = t
    const float kx = kps_trg[((size_t)b * N_ + t) * 2 + 0];
    const float ky = kps_trg[((size_t)b * N_ + t) * 2 + 1];
    const float gx = kx * (1.f / 16.f), gy = ky * (1.f / 16.f);
    const int x0 = (int)fminf(fmaxf(floorf(gx), 0.f), 63.f);
    const int y0 = (int)fminf(fmaxf(floorf(gy), 0.f), 63.f);
    const int x1 = min(x0 + 1, 63), y1 = min(y0 + 1, 63);
    const float x0f = (float)x0, x1f = (float)x1, y0f = (float)y0, y1f = (float)y1;
    const float mk = (mask[(size_t)b * N_ + t] != 0) ? 1.f : 0.f;
    tidx[t][0] = y0 * WF + x0; tw[t][0] = (x1f - gx) * (y1f - gy) * mk;
    tidx[t][1] = y1 * WF + x0; tw[t][1] = (x1f - gx) * (gy - y0f) * mk;
    tidx[t][2] = y0 * WF + x1; tw[t][2] = (gx - x0f) * (y1f - gy) * mk;
    tidx[t][3] = y1 * WF + x1; tw[t][3] = (gx - x0f) * (gy - y0f) * mk;
  }
  __syncthreads();

  float scj[4];
#pragma unroll
  for (int j = 0; j < 4; j++) scj[j] = scl[wm * 64 + j * 16 + ln];
#pragma unroll
  for (int i = 0; i < 4; i++)
#pragma unroll
    for (int j = 0; j < 4; j++) acc[i][j] *= scj[j];

  // --- per-row (max, sumexp) over this wave's 64 m, then target-logit extraction ---
#pragma unroll
  for (int i = 0; i < 4; i++) {
#pragma unroll
    for (int r = 0; r < 4; r++) {
      float mx = fmaxf(fmaxf(acc[i][0][r], acc[i][1][r]), fmaxf(acc[i][2][r], acc[i][3][r]));
#pragma unroll
      for (int msk = 1; msk < 16; msk <<= 1) mx = fmaxf(mx, __shfl_xor(mx, msk, 64));
      float sm = __expf(acc[i][0][r] - mx) + __expf(acc[i][1][r] - mx) +
                 __expf(acc[i][2][r] - mx) + __expf(acc[i][3][r] - mx);
#pragma unroll
      for (int msk = 1; msk < 16; msk <<= 1) sm += __shfl_xor(sm, msk, 64);
      if (ln == 0) lser[(wn * 64 + i * 16 + lg * 4 + r) * 2 + wm] = make_float2(mx, sm);

      const int n = wn * 64 + i * 16 + lg * 4 + r;
      const int4  id4 = *(const int4*)&tidx[n][0];
      const float4 w4 = *(const float4*)&tw[n][0];
      const int   ida[4] = {id4.x, id4.y, id4.z, id4.w};
      const float wwa[4] = {w4.x, w4.y, w4.z, w4.w};
#pragma unroll
      for (int j = 0; j < 4; j++) {
        const int mg = m0 + wm * 64 + j * 16 + ln;
        const float lv = acc[i][j][r];
#pragma unroll
        for (int cc = 0; cc < 4; cc++)
          if (ida[cc] == mg && wwa[cc] != 0.f)
            atomicAdd(&tacc[(size_t)b * N_ + n], wwa[cc] * lv);
      }
    }
  }
  __syncthreads();
  if (t < 128) {
    const float2 u = lser[t * 2 + 0], v = lser[t * 2 + 1];
    const float M = fmaxf(u.x, v.x);
    const float S = u.y * __expf(u.x - M) + v.y * __expf(v.x - M);
    part[((size_t)b * N_ + t) * NCH + mb] = make_float2(M, S);
  }
}

// ============ k4: per-(b,n) loss combine + masked-sum atomics ============
__global__ __launch_bounds__(128) void k4_comb(const float2* __restrict__ part,
                                               const float* __restrict__ tacc,
                                               const float* __restrict__ kps_trg,
                                               const int* __restrict__ mask,
                                               float* __restrict__ gs) {
  const int b = blockIdx.x, t = threadIdx.x;  // t = n
  const float2* p = part + ((size_t)b * N_ + t) * NCH;
  float M = -INFINITY;
#pragma unroll 8
  for (int c = 0; c < NCH; c++) M = fmaxf(M, p[c].x);
  float S = 0.f;
#pragma unroll 8
  for (int c = 0; c < NCH; c++) S += p[c].y * __expf(p[c].x - M);
  const float lse = M + logf(S);

  const float kx = kps_trg[((size_t)b * N_ + t) * 2 + 0];
  const float ky = kps_trg[((size_t)b * N_ + t) * 2 + 1];
  const float gx = kx * (1.f / 16.f), gy = ky * (1.f / 16.f);
  const int x0 = (int)fminf(fmaxf(floorf(gx), 0.f), 63.f);
  const int y0 = (int)fminf(fmaxf(floorf(gy), 0.f), 63.f);
  const int x1 = min(x0 + 1, 63), y1 = min(y0 + 1, 63);
  const float mk = (mask[(size_t)b * N_ + t] != 0) ? 1.f : 0.f;
  const float wsum = (float)(x1 - x0) * (float)(y1 - y0) * mk;

  float loss = wsum * lse - tacc[(size_t)b * N_ + t];
  float cnt = mk;
  loss = wave_sum(loss);
  cnt = wave_sum(cnt);
  __shared__ float sl[2], sc2[2];
  if ((t & 63) == 0) { sl[t >> 6] = loss; sc2[t >> 6] = cnt; }
  __syncthreads();
  if (t == 0) {
    atomicAdd(&gs[0], sl[0] + sl[1]);
    atomicAdd(&gs[1], sc2[0] + sc2[1]);
  }
}

__global__ void k5_final(const float* __restrict__ gs, float* __restrict__ out) {
  out[0] = gs[0] / fmaxf(gs[1], 1.f);
}

extern "C" void kernel_launch(void* const* d_in, const int* in_sizes, int n_in,
                              void* d_out, int out_size, void* d_ws, size_t ws_size,
                              hipStream_t stream) {
  const float* feats_src = (const float*)d_in[0];
  const float* feats_trg = (const float*)d_in[1];
  const float* kps_src   = (const float*)d_in[2];
  const float* kps_trg   = (const float*)d_in[3];
  const int*   kps_mask  = (const int*)d_in[4];
  float* out = (float*)d_out;

  // ws layout (bytes):
  //   0            ssqg   : B*N*4 floats          = 65536
  //   65536        tacc   : B*N floats            = 16384
  //   81920        gs     : 2 floats              = 8
  //   82432        corner : B*C*N*4 ushort        = 8388608
  //   8471040      qbf    : B*N*C ushort          = 2097152
  //   10568192     part   : B*N*NCH float2        = 1048576
  //   total ~11.6 MB
  char* wsb = (char*)d_ws;
  float*  ssqg   = (float*)(wsb + 0);
  float*  tacc   = (float*)(wsb + 65536);
  float*  gs     = (float*)(wsb + 81920);
  ushort* corner = (ushort*)(wsb + 82432);
  ushort* qbf    = (ushort*)(wsb + 8471040);
  float2* part   = (float2*)(wsb + 10568192);

  hipMemsetAsync(wsb, 0, 81928, stream);  // zero ssqg + tacc + gs

  k1a_stage<<<dim3(C_ / 2, B_), 256, 0, stream>>>(feats_src, kps_src, corner, ssqg);
  k1b_combine<<<dim3(N_, B_), 256, 0, stream>>>(corner, ssqg, kps_src, qbf);
  k2_mfma<<<dim3(NCH, B_), 256, 0, stream>>>(feats_trg, qbf, kps_trg, kps_mask, part, tacc);
  k4_comb<<<dim3(B_), 128, 0, stream>>>(part, tacc, kps_trg, kps_mask, gs);
  k5_final<<<1, 1, 0, stream>>>(gs, out);
}